// Round 1
// baseline (755.858 us; speedup 1.0000x reference)
//
#include <hip/hip_runtime.h>

// GeodesicLoss: outputs(B,D) f32, targets(B,D) f32, gamma(B,D,D,D) f32 -> scalar f32
// B=256, D=64, NUM_STEPS=10 (RK2 midpoint integration).
// Strategy: symmetric-pack gamma once (2080/4096 entries per row), then 20
// accel passes read the packed copy (fits in 256MB Infinity Cache).

#define NSTEPS 10
#define BATCH 256
#define DIM 64
#define TPB 1024
#define ROWLEN 4096              // DIM*DIM
#define NPACK 2080               // DIM*(DIM+1)/2
#define WS_ACC_FLOATS 64         // accumulator header in ws (256 B)

__device__ __forceinline__ float waveSum(float v) {
    // butterfly across all 64 lanes; every lane gets the total
    #pragma unroll
    for (int off = 32; off; off >>= 1) v += __shfl_xor(v, off, 64);
    return v;
}

__global__ void init_ws_kernel(unsigned* ws) {
    if (threadIdx.x < 4) ws[threadIdx.x] = 0u;   // [0]=geo, [1]=euclid (f32 0.0), [2]=flag
}

__global__ __launch_bounds__(TPB, 1)
void geo_main_kernel(const float* __restrict__ x0g,
                     const float* __restrict__ x1g,
                     const float* __restrict__ gam,
                     float* __restrict__ ws,      // accumulators
                     float* __restrict__ pack,    // packed buffer (after header)
                     int use_pack)
{
    __shared__ float vel[DIM];
    __shared__ float mvel[DIM];
    __shared__ float acc[DIM];
    __shared__ float wp[ROWLEN];          // outer-product table (first L entries used)
    __shared__ uchar2 lut[NPACK];         // packed idx -> (j,k)
    __shared__ float rowbuf[2][ROWLEN];   // pack-phase staging (double buffered)

    const int b    = blockIdx.x;
    const int t    = threadIdx.x;
    const int wave = t >> 6;
    const int lane = t & 63;
    const float dt = 1.0f / NSTEPS;

    // ---- build (j,k) LUT for packed indexing ----
    for (int e = t; e < ROWLEN; e += TPB) {
        int j = e >> 6, k = e & 63;
        if (k >= j) {
            int idx = j * DIM - (j * (j - 1)) / 2 + (k - j);
            lut[idx] = make_uchar2((unsigned char)j, (unsigned char)k);
        }
    }

    // ---- wave 0: initial velocity, trajectory, euclid contribution ----
    float x1r = 0.f, fpPrev = 0.f, fpCur = 0.f, trajr = 0.f;
    if (wave == 0) {
        float x0r = x0g[b * DIM + lane];
        x1r       = x1g[b * DIM + lane];
        float d0  = x1r - x0r;
        float nrm = sqrtf(waveSum(d0 * d0));          // ||x1-x0||
        if (lane == 0) atomicAdd(&ws[1], nrm * (1.0f / BATCH));
        float v  = d0 * dt;                            // (x1-x0)/S
        float nv = nrm * dt;                           // ||v||
        v = v / (nv + 1e-8f);
        vel[lane] = v;
        trajr  = x0r;
        fpCur  = x0r;   // full_path[0]
    }
    __syncthreads();

    unsigned nzflag = 0;

    // ---- pack phase: read raw gamma once, write symmetrized packed copy ----
    if (use_pack) {
        const float4* g4 = (const float4*)(gam + (size_t)b * DIM * ROWLEN);
        float4 pre = g4[t];                            // prefetch row 0
        for (int i = 0; i < DIM; ++i) {
            ((float4*)rowbuf[i & 1])[t] = pre;
            nzflag |= (pre.x != 0.f) | (pre.y != 0.f) | (pre.z != 0.f) | (pre.w != 0.f);
            __syncthreads();
            if (i + 1 < DIM) pre = g4[(size_t)(i + 1) * (ROWLEN / 4) + t];  // prefetch next row
            const float* rb = rowbuf[i & 1];
            float* prow = pack + ((size_t)b * DIM + i) * NPACK;
            #pragma unroll
            for (int rep = 0; rep < 3; ++rep) {
                int e = t + rep * TPB;
                if (e < NPACK) {
                    uchar2 jk = lut[e];
                    float vsym = rb[jk.x * DIM + jk.y];
                    if (jk.x != jk.y) vsym += rb[jk.y * DIM + jk.x];
                    prow[e] = vsym;
                }
            }
            __syncthreads();
        }
    }

    const float* mat = use_pack ? pack + (size_t)b * DIM * NPACK
                                : gam  + (size_t)b * DIM * ROWLEN;
    const int L = use_pack ? NPACK : ROWLEN;

    // ---- generic accel evaluation: vsrc (LDS) -> acc (LDS) ----
    auto accel = [&](const float* vsrc, bool doflag) {
        __syncthreads();                 // vsrc ready; previous wp consumers done
        for (int e = t; e < L; e += TPB) {
            int j, k;
            if (use_pack) { uchar2 jk = lut[e]; j = jk.x; k = jk.y; }
            else          { j = e >> 6; k = e & 63; }
            wp[e] = vsrc[j] * vsrc[k];
        }
        __syncthreads();
        const int full = L >> 6;         // 32 (packed) or 64 (raw) full wave-iters
        #pragma unroll
        for (int rr = 0; rr < 4; ++rr) {
            const int i = wave * 4 + rr;
            const float* mrow = mat + (size_t)i * L;
            float s = 0.f;
            for (int u = 0; u < full; ++u) {
                float g = mrow[lane + (u << 6)];
                if (doflag) nzflag |= (g != 0.f);
                s += g * wp[lane + (u << 6)];
            }
            int rem = lane + (full << 6);   // ragged tail (packed: lanes < 32)
            if (rem < L) {
                float g = mrow[rem];
                if (doflag) nzflag |= (g != 0.f);
                s += g * wp[rem];
            }
            s = waveSum(s);
            if (lane == 0) acc[i] = -s;
        }
        __syncthreads();
    };

    // ---- RK2 integration ----
    float smooth = 0.f;
    for (int s = 0; s < NSTEPS; ++s) {
        accel(vel, (!use_pack) && (s == 0));           // a1 = A(vel)
        if (wave == 0) mvel[lane] = vel[lane] + 0.5f * dt * acc[lane];
        accel(mvel, false);                            // a2 = A(mid_vel)
        if (wave == 0) {
            float vnew = vel[lane] + dt * acc[lane];
            vel[lane]  = vnew;
            float fpNext = trajr + dt * vnew;
            trajr = fpNext;
            if (s >= 1) {
                float sec = fpNext - 2.f * fpCur + fpPrev;
                smooth += sqrtf(waveSum(sec * sec));
            }
            fpPrev = fpCur;
            fpCur  = fpNext;
        }
    }

    // ---- nonzero flag (full gamma was scanned either in pack or first accel) ----
    unsigned long long bal = __ballot(nzflag != 0);
    if (lane == 0 && bal) atomicOr((unsigned*)ws + 2, 1u);

    // ---- per-batch geodesic contribution ----
    if (wave == 0) {
        float dl  = trajr - x1r;
        float tgt = sqrtf(waveSum(dl * dl));
        if (lane == 0) atomicAdd(&ws[0], (tgt + 0.1f * smooth) * (1.0f / BATCH));
    }
}

__global__ void finalize_kernel(const float* ws, float* out) {
    unsigned flag = ((const unsigned*)ws)[2];
    out[0] = flag ? ws[0] : ws[1];
}

extern "C" void kernel_launch(void* const* d_in, const int* in_sizes, int n_in,
                              void* d_out, int out_size, void* d_ws, size_t ws_size,
                              hipStream_t stream) {
    const float* x0  = (const float*)d_in[0];   // outputs
    const float* x1  = (const float*)d_in[1];   // targets
    const float* gam = (const float*)d_in[2];   // christoffel_symbols
    float* ws   = (float*)d_ws;
    float* pack = (float*)((char*)d_ws + WS_ACC_FLOATS * sizeof(float));

    const size_t need = WS_ACC_FLOATS * sizeof(float)
                      + (size_t)BATCH * DIM * NPACK * sizeof(float);
    const int use_pack = (ws_size >= need) ? 1 : 0;

    init_ws_kernel<<<1, 64, 0, stream>>>((unsigned*)ws);
    geo_main_kernel<<<BATCH, TPB, 0, stream>>>(x0, x1, gam, ws, pack, use_pack);
    finalize_kernel<<<1, 1, 0, stream>>>(ws, (float*)d_out);
}